// Round 1
// baseline (558.242 us; speedup 1.0000x reference)
//
#include <hip/hip_runtime.h>
#include <hip/hip_bf16.h>
#include <stdint.h>
#include <stddef.h>

// Problem constants (from reference setup_inputs)
#define N_NODES 8192
#define DIM     256
#define BATCH   4096
#define CLASSES 1000
#define ALPHA_C 1.0f
#define BETA_C  0.01f
#define GAMMA_C 0.1f
#define COS_EPS 1e-8f

typedef __bf16 bf16_t;
typedef __bf16 bf16x8 __attribute__((ext_vector_type(8)));
typedef float  f32x4  __attribute__((ext_vector_type(4)));

// ---------------------------------------------------------------------------
// Prep: per-row L2 norm (fp32) + bf16 cast of embeddings into workspace.
// One block (256 threads) per row; DIM == 256 so one element per thread.
// ---------------------------------------------------------------------------
__global__ __launch_bounds__(256) void prep_kernel(
    const float* __restrict__ emb, bf16_t* __restrict__ U,
    float* __restrict__ norms) {
  const int row = blockIdx.x;
  const int t = threadIdx.x;
  float v = emb[(size_t)row * DIM + t];
  U[(size_t)row * DIM + t] = (bf16_t)v;
  float sq = v * v;
  for (int off = 32; off; off >>= 1) sq += __shfl_down(sq, off);
  __shared__ float red[4];
  const int wave = t >> 6, lane = t & 63;
  if (lane == 0) red[wave] = sq;
  __syncthreads();
  if (t == 0) {
    float s = red[0] + red[1] + red[2] + red[3];
    norms[row] = sqrtf(s);
  }
}

// ---------------------------------------------------------------------------
// Cross-entropy: one block (256 threads) per batch row. logsumexp - logit[t].
// Accumulates ALPHA/B * loss into out[0] via atomicAdd.
// ---------------------------------------------------------------------------
__global__ __launch_bounds__(256) void ce_kernel(
    const float* __restrict__ pred, const int* __restrict__ target,
    float* __restrict__ out) {
  const int row = blockIdx.x;
  const int t = threadIdx.x;
  const float* p = pred + (size_t)row * CLASSES;

  float m = -INFINITY;
  for (int c = t; c < CLASSES; c += 256) m = fmaxf(m, p[c]);
  for (int off = 32; off; off >>= 1) m = fmaxf(m, __shfl_down(m, off));

  __shared__ float red[8];
  const int wave = t >> 6, lane = t & 63;
  if (lane == 0) red[wave] = m;
  __syncthreads();
  if (t == 0) red[4] = fmaxf(fmaxf(red[0], red[1]), fmaxf(red[2], red[3]));
  __syncthreads();
  const float mx = red[4];

  float s = 0.f;
  for (int c = t; c < CLASSES; c += 256) s += __expf(p[c] - mx);
  for (int off = 32; off; off >>= 1) s += __shfl_down(s, off);
  if (lane == 0) red[wave] = s;
  __syncthreads();
  if (t == 0) {
    float ssum = red[0] + red[1] + red[2] + red[3];
    float lse = mx + __logf(ssum);
    float loss = lse - p[target[row]];
    atomicAdd(out, loss * (ALPHA_C / (float)BATCH));
  }
}

// ---------------------------------------------------------------------------
// Fused Gram + weighted reduction:
//   out += sum_{tile} [ BETA*|a_ij| + GAMMA*a_ij*(1 - dot_ij/max(n_i*n_j,eps)) ] / N^2
// Block tile 64x64, full K=256 staged in LDS (bf16). 4 waves, each 32x32 via
// 2x2 grid of 16x16x32 bf16 MFMAs. adj read directly from global in epilogue.
// LDS row stride padded to 264 elems (528 B -> bank offset 4/row: 2-way, free).
// ---------------------------------------------------------------------------
#define BT  64
#define LDA 264

__global__ __launch_bounds__(256) void gram_kernel(
    const float* __restrict__ adj, const bf16_t* __restrict__ U,
    const float* __restrict__ norms, float* __restrict__ out) {
  __shared__ __align__(16) bf16_t As[BT * LDA];
  __shared__ __align__(16) bf16_t Bs[BT * LDA];

  const int bi = blockIdx.y, bj = blockIdx.x;
  const int i0 = bi * BT, j0 = bj * BT;
  const int t = threadIdx.x;

  // Stage A (rows i0..i0+63) and B (rows j0..j0+63), full K, 16 B per thread
  // per iter: 32 threads/row, 8 rows/iter, 8 iters.
  {
    const int tr = t >> 5;   // 0..7
    const int tc = t & 31;   // 0..31
    for (int it = 0; it < 8; ++it) {
      const int r = it * 8 + tr;
      *(uint4*)(&As[r * LDA + tc * 8]) =
          *(const uint4*)(U + (size_t)(i0 + r) * DIM + tc * 8);
      *(uint4*)(&Bs[r * LDA + tc * 8]) =
          *(const uint4*)(U + (size_t)(j0 + r) * DIM + tc * 8);
    }
  }
  __syncthreads();

  const int wave = t >> 6;
  const int lane = t & 63;
  const int wr = (wave >> 1) * 32;  // wave's row offset within block tile
  const int wc = (wave & 1) * 32;   // wave's col offset
  const int fr = lane & 15;         // fragment m/n index
  const int fq = lane >> 4;         // quad -> k offset fq*8 (A/B), row fq*4 (C/D)

  f32x4 acc[2][2] = {};
  for (int k0 = 0; k0 < DIM; k0 += 32) {
    bf16x8 a[2], b[2];
    for (int ms = 0; ms < 2; ++ms)
      a[ms] = *(const bf16x8*)(&As[(wr + ms * 16 + fr) * LDA + k0 + fq * 8]);
    for (int ns = 0; ns < 2; ++ns)
      b[ns] = *(const bf16x8*)(&Bs[(wc + ns * 16 + fr) * LDA + k0 + fq * 8]);
    for (int ms = 0; ms < 2; ++ms)
      for (int ns = 0; ns < 2; ++ns)
        acc[ms][ns] = __builtin_amdgcn_mfma_f32_16x16x32_bf16(
            a[ms], b[ns], acc[ms][ns], 0, 0, 0);
  }

  // Epilogue: C/D layout col=lane&15, row=(lane>>4)*4+reg.
  float local = 0.f;
  for (int ms = 0; ms < 2; ++ms) {
    for (int ns = 0; ns < 2; ++ns) {
      const int ibase = i0 + wr + ms * 16 + fq * 4;
      const int jj = j0 + wc + ns * 16 + fr;
      const float nj = norms[jj];
      for (int r = 0; r < 4; ++r) {
        const int ii = ibase + r;
        const float dot = acc[ms][ns][r];
        const float sim = dot / fmaxf(norms[ii] * nj, COS_EPS);
        const float a = adj[(size_t)ii * N_NODES + jj];
        local += BETA_C * fabsf(a) + GAMMA_C * a * (1.f - sim);
      }
    }
  }

  for (int off = 32; off; off >>= 1) local += __shfl_down(local, off);
  __shared__ float red[4];
  if (lane == 0) red[wave] = local;
  __syncthreads();
  if (t == 0) {
    const float inv = 1.f / ((float)N_NODES * (float)N_NODES);
    atomicAdd(out, (red[0] + red[1] + red[2] + red[3]) * inv);
  }
}

// ---------------------------------------------------------------------------
extern "C" void kernel_launch(void* const* d_in, const int* in_sizes, int n_in,
                              void* d_out, int out_size, void* d_ws,
                              size_t ws_size, hipStream_t stream) {
  const float* pred   = (const float*)d_in[0];
  const int*   target = (const int*)d_in[1];
  const float* adj    = (const float*)d_in[2];
  const float* emb    = (const float*)d_in[3];
  float* out = (float*)d_out;

  // Workspace: bf16 embeddings (4 MB) then norms (32 KB).
  bf16_t* U     = (bf16_t*)d_ws;
  float*  norms = (float*)((char*)d_ws + (size_t)N_NODES * DIM * sizeof(bf16_t));

  hipMemsetAsync(d_out, 0, sizeof(float), stream);
  prep_kernel<<<N_NODES, 256, 0, stream>>>(emb, U, norms);
  ce_kernel<<<BATCH, 256, 0, stream>>>(pred, target, out);
  gram_kernel<<<dim3(N_NODES / BT, N_NODES / BT), 256, 0, stream>>>(
      adj, U, norms, out);
}